// Round 8
// baseline (888.087 us; speedup 1.0000x reference)
//
#include <hip/hip_runtime.h>
#include <hip/hip_bf16.h>
#include <math.h>

#define BATCH 32
#define NTOK 577
#define DIM 768
#define NHEAD 12
#define HDIM 64
#define MLP 3072
#define ROWS (BATCH*NTOK)
#define ATTN_SCALE 0.125f
#define LN_EPS 1e-6f
#define VST 584
#define RST 584
#define TK 64
#define NRT2 73   // row tiles of 256 over 18464 rows
#define SOFF 20.0f

typedef unsigned short u16;
typedef unsigned int u32;
typedef __attribute__((ext_vector_type(8))) short bf16x8;
typedef __attribute__((ext_vector_type(4))) float f32x4;
typedef const __attribute__((address_space(3))) u16* lds_cp;

__device__ inline u16 f2bf(float f){
  u32 u = __float_as_uint(f);
  u32 r = (u + 0x7fffu + ((u>>16)&1u)) >> 16;
  return (u16)r;
}
__device__ inline float bf2f(u16 v){
  u32 u = ((u32)v)<<16; return __uint_as_float(u);
}

__device__ __forceinline__ void gload16(const u16* g, u16* l){
  __builtin_amdgcn_global_load_lds((const __attribute__((address_space(1))) void*)g,
                                   (__attribute__((address_space(3))) void*)l, 16, 0, 0);
}

// exact-erf GELU via A&S 7.1.26 rational approx (|err| < 1.5e-7)
__device__ inline float gelu_f(float v){
  float xa = fabsf(v)*0.70710678118654752f;
  float t = 1.0f/(1.0f + 0.3275911f*xa);
  float p = (((1.061405429f*t - 1.453152027f)*t + 1.421413741f)*t - 0.284496736f)*t + 0.254829592f;
  float erfv = 1.0f - p*t*__expf(-xa*xa);
  erfv = (v < 0.f) ? -erfv : erfv;
  return 0.5f*v*(1.0f + erfv);
}

// ---- fused weight conversion f32 -> bf16 ----
__global__ void cvt4_kernel(const float* __restrict__ s0, int n0,
                            const float* __restrict__ s1, int n1,
                            const float* __restrict__ s2, int n2,
                            const float* __restrict__ s3, int n3,
                            u16* __restrict__ d0, u16* __restrict__ d1,
                            u16* __restrict__ d2, u16* __restrict__ d3){
  int i = blockIdx.x*256 + threadIdx.x;
  if(i < n0){ d0[i] = f2bf(s0[i]); return; }
  i -= n0;
  if(i < n1){ d1[i] = f2bf(s1[i]); return; }
  i -= n1;
  if(i < n2){ d2[i] = f2bf(s2[i]); return; }
  i -= n2;
  if(i < n3){ d3[i] = f2bf(s3[i]); }
}

// ---- rpb precompute (bf16, padded row stride 584) ----
__global__ void rpb_kernel(const int* __restrict__ rel, const float* __restrict__ table, u16* __restrict__ bias){
  int i = blockIdx.x*256 + threadIdx.x;
  const int nm = NTOK*NTOK;
  if(i >= NHEAD*nm) return;
  int h = i / nm;
  int r = i - h*nm;
  int n = r / NTOK, m = r - n*NTOK;
  bias[((size_t)h*NTOK + n)*RST + m] = f2bf(table[rel[r]*NHEAD + h]);
}

// ---- LayerNorm ----
__global__ __launch_bounds__(256) void ln_kernel(const float* __restrict__ in, const float* __restrict__ g,
                                                 const float* __restrict__ b, u16* __restrict__ out){
  int row = blockIdx.x;
  const float* p = in + (size_t)row*DIM;
  int t = threadIdx.x;
  float v0 = p[t], v1 = p[t+256], v2 = p[t+512];
  float s = v0+v1+v2;
  #pragma unroll
  for(int off=32; off; off>>=1) s += __shfl_xor(s, off);
  __shared__ float red[8];
  int wv = t>>6;
  if((t&63)==0) red[wv] = s;
  __syncthreads();
  float mean = (red[0]+red[1]+red[2]+red[3]) * (1.0f/768.0f);
  float d0=v0-mean, d1=v1-mean, d2=v2-mean;
  float q = d0*d0 + d1*d1 + d2*d2;
  #pragma unroll
  for(int off=32; off; off>>=1) q += __shfl_xor(q, off);
  if((t&63)==0) red[4+wv] = q;
  __syncthreads();
  float var = (red[4]+red[5]+red[6]+red[7]) * (1.0f/768.0f);
  float inv = rsqrtf(var + LN_EPS);
  u16* po = out + (size_t)row*DIM;
  po[t]     = f2bf(d0*inv*g[t]     + b[t]);
  po[t+256] = f2bf(d1*inv*g[t+256] + b[t+256]);
  po[t+512] = f2bf(d2*inv*g[t+512] + b[t+512]);
}

// ---- 256x256 bf16 MFMA GEMM, 4-phase/K-tile counted-vmcnt schedule.
// == round-3 kernel with ONE change: fragment loads are inline-asm
// ds_read_b128 (r7's proven fix). r3's pointer-deref reads caused
// SIInsertWaitcnts to insert hidden vmcnt(0) drains (LDS-DMA aliasing),
// nullifying the counted-wait chain; asm reads are opaque to that pass,
// so the verified schedule finally executes as written:
//   stage pair X(t+1) at {ph0:A-lo, ph1:B-lo, ph2:B-hi, ph3:A-hi};
//   waits vmcnt(4) at ph0/ph1/ph3 retire exactly {B-hi(t), A-hi(t),
//   A-lo/B-lo(t+1)}; steady outstanding <= 8; never vmcnt(0) mid-loop.
// ds_reads issued BEFORE the mid barrier (latency hides under barrier
// skew), lgkmcnt(0)+sched_barrier(0) after it (rule #18), setprio(1)
// around MFMA clusters (T5, active in 8-phase regime). 24 ds_read/wave/
// K-tile, B frags held across phases. LDS XOR-swizzle (0 conflicts,
// verified r2-r7) via inverse-swizzled global source + linear glds dest. ----
template<int MODE, int NC>
__global__ __launch_bounds__(512, 1) void gemm_kernel(
    const u16* __restrict__ A, const u16* __restrict__ Bt,
    int M, int K,
    const float* __restrict__ b0, const float* __restrict__ b1,
    const float* __restrict__ resid, float* __restrict__ outf,
    u16* __restrict__ o0, u16* __restrict__ o1, u16* __restrict__ o2)
{
  __shared__ __align__(16) u16 Asb[2][256*64];
  __shared__ __align__(16) u16 Bsb[2][256*64];

  // bijective XCD-aware swizzle (m204)
  const int nwg = gridDim.x;
  const int q8 = nwg >> 3, r8 = nwg & 7;
  const int xcd = blockIdx.x & 7, lid = blockIdx.x >> 3;
  const int wg = (xcd < r8 ? xcd*(q8+1) : r8*(q8+1) + (xcd - r8)*q8) + lid;
  const int rT = wg / NC, cT = wg - rT*NC;
  const int tileRow = rT*256, tileCol = cT*256;

  const int tx = threadIdx.x;
  const int wave = tx>>6, lane = tx&63;
  const int wr = wave>>2, wc = wave&3;          // wave -> (M half, N quarter)
  const int wcB = wave>>1, sub2 = wave&1;       // B staging ownership
  const int l15 = lane&15, kq = lane>>4, l7 = lane&7;
  const int csub = lane>>3;                     // staging sub-row 0..7
  const u32 cperm = 8u*(u32)(l7 ^ csub);        // inverse-swizzled source col (elems)
  const int c0 = (kq*8) ^ (l7*8);               // swizzled frag col (elems), k-half0

  // staging geometry
  const int RSA0 = wr*128 + wc*16, RSA1 = RSA0 + 64;
  const int RSB0 = wcB*64 + sub2*16, RSB1 = RSB0 + 32;
  int ra = tileRow + RSA0 + csub;
  const u32 offA00 = (u32)min(ra,   M-1)*(u32)K + cperm;
  const u32 offA01 = (u32)min(ra+8, M-1)*(u32)K + cperm;
  ra = tileRow + RSA1 + csub;
  const u32 offA10 = (u32)min(ra,   M-1)*(u32)K + cperm;
  const u32 offA11 = (u32)min(ra+8, M-1)*(u32)K + cperm;
  const u32 offB00 = (u32)(tileCol + RSB0 + csub)*(u32)K + cperm;
  const u32 offB01 = offB00 + 8u*(u32)K;
  const u32 offB10 = (u32)(tileCol + RSB1 + csub)*(u32)K + cperm;
  const u32 offB11 = offB10 + 8u*(u32)K;
  const int dA0 = RSA0*64, dA1 = RSA1*64, dB0 = RSB0*64, dB1 = RSB1*64;

  f32x4 acc[8][4];
  #pragma unroll
  for(int i=0;i<8;i++)
    #pragma unroll
    for(int j=0;j<4;j++){ f32x4 z = {0.f,0.f,0.f,0.f}; acc[i][j]=z; }

  // prologue: stage tile 0 into buf0, order A-lo, B-lo, B-hi, A-hi
  {
    u16* a = &Asb[0][0]; u16* bs = &Bsb[0][0];
    gload16(A  + offA00, a  + dA0);
    gload16(A  + offA01, a  + dA0 + 512);
    gload16(Bt + offB00, bs + dB0);
    gload16(Bt + offB01, bs + dB0 + 512);
    gload16(Bt + offB10, bs + dB1);
    gload16(Bt + offB11, bs + dB1 + 512);
    gload16(A  + offA10, a  + dA1);
    gload16(A  + offA11, a  + dA1 + 512);
  }
  asm volatile("s_waitcnt vmcnt(4)" ::: "memory");   // A-lo,B-lo(0) complete
  __builtin_amdgcn_s_barrier();                      // publish

  const int NT = K >> 6;
  bf16x8 af[4][2], bgA[2][2], bgB[2][2];

  #define DSR(dst, base, off) { \
    lds_cp p_ = (lds_cp)((base) + (off)); \
    asm volatile("ds_read_b128 %0, %1" : "=v"(dst) : "v"(p_)); \
  }

  for(int t=0; t<NT; ++t){
    const int cur = t & 1;
    u16* curA = &Asb[cur][0];   u16* curB = &Bsb[cur][0];
    u16* nxtA = &Asb[cur^1][0]; u16* nxtB = &Bsb[cur^1][0];
    const bool pf = (t+1 < NT);
    const u32 kkN = (u32)(t+1) << 6;

    // ---------------- phase 0: m0-3 x n0-1 ----------------
    #pragma unroll
    for(int m=0;m<4;m++){
      const int rb = (wr*128 + m*16 + l15)*64;
      DSR(af[m][0], curA, rb + c0);
      DSR(af[m][1], curA, rb + (c0^32));
    }
    #pragma unroll
    for(int n=0;n<2;n++){
      const int rb = (wc*64 + n*16 + l15)*64;
      DSR(bgA[n][0], curB, rb + c0);
      DSR(bgA[n][1], curB, rb + (c0^32));
    }
    if(pf){ gload16(A + (offA00 + kkN), nxtA + dA0);
            gload16(A + (offA01 + kkN), nxtA + dA0 + 512);
            asm volatile("s_waitcnt vmcnt(4)" ::: "memory"); }   // B-hi(t) done
    else  { asm volatile("s_waitcnt vmcnt(2)" ::: "memory"); }
    __builtin_amdgcn_s_barrier();
    asm volatile("s_waitcnt lgkmcnt(0)" ::: "memory");
    __builtin_amdgcn_sched_barrier(0);
    __builtin_amdgcn_s_setprio(1);
    #pragma unroll
    for(int m=0;m<4;m++)
      #pragma unroll
      for(int n=0;n<2;n++){
        acc[m][n] = __builtin_amdgcn_mfma_f32_16x16x32_bf16(af[m][0], bgA[n][0], acc[m][n], 0,0,0);
        acc[m][n] = __builtin_amdgcn_mfma_f32_16x16x32_bf16(af[m][1], bgA[n][1], acc[m][n], 0,0,0);
      }
    __builtin_amdgcn_s_setprio(0);
    __builtin_amdgcn_s_barrier();

    // ---------------- phase 1: m0-3 x n2-3 (B-hi; af reused) ----------------
    #pragma unroll
    for(int n=0;n<2;n++){
      const int rb = (wc*64 + 32 + n*16 + l15)*64;
      DSR(bgB[n][0], curB, rb + c0);
      DSR(bgB[n][1], curB, rb + (c0^32));
    }
    if(pf){ gload16(Bt + (offB00 + kkN), nxtB + dB0);
            gload16(Bt + (offB01 + kkN), nxtB + dB0 + 512);
            asm volatile("s_waitcnt vmcnt(4)" ::: "memory"); }   // A-hi(t) done
    else  { asm volatile("s_waitcnt vmcnt(0)" ::: "memory"); }   // drain
    __builtin_amdgcn_s_barrier();
    asm volatile("s_waitcnt lgkmcnt(0)" ::: "memory");
    __builtin_amdgcn_sched_barrier(0);
    __builtin_amdgcn_s_setprio(1);
    #pragma unroll
    for(int m=0;m<4;m++)
      #pragma unroll
      for(int n=0;n<2;n++){
        acc[m][2+n] = __builtin_amdgcn_mfma_f32_16x16x32_bf16(af[m][0], bgB[n][0], acc[m][2+n], 0,0,0);
        acc[m][2+n] = __builtin_amdgcn_mfma_f32_16x16x32_bf16(af[m][1], bgB[n][1], acc[m][2+n], 0,0,0);
      }
    __builtin_amdgcn_s_setprio(0);
    __builtin_amdgcn_s_barrier();

    // ---------------- phase 2: m4-7 x n0-1 (A-hi; bgA reused) ----------------
    #pragma unroll
    for(int m=0;m<4;m++){
      const int rb = (wr*128 + 64 + m*16 + l15)*64;
      DSR(af[m][0], curA, rb + c0);
      DSR(af[m][1], curA, rb + (c0^32));
    }
    if(pf){ gload16(Bt + (offB10 + kkN), nxtB + dB1);
            gload16(Bt + (offB11 + kkN), nxtB + dB1 + 512); }
    __builtin_amdgcn_s_barrier();
    asm volatile("s_waitcnt lgkmcnt(0)" ::: "memory");
    __builtin_amdgcn_sched_barrier(0);
    __builtin_amdgcn_s_setprio(1);
    #pragma unroll
    for(int m=0;m<4;m++)
      #pragma unroll
      for(int n=0;n<2;n++){
        acc[4+m][n] = __builtin_amdgcn_mfma_f32_16x16x32_bf16(af[m][0], bgA[n][0], acc[4+m][n], 0,0,0);
        acc[4+m][n] = __builtin_amdgcn_mfma_f32_16x16x32_bf16(af[m][1], bgA[n][1], acc[4+m][n], 0,0,0);
      }
    __builtin_amdgcn_s_setprio(0);
    __builtin_amdgcn_s_barrier();

    // ---------------- phase 3: m4-7 x n2-3 (af, bgB reused; no reads) ----------------
    if(pf){ gload16(A + (offA10 + kkN), nxtA + dA1);
            gload16(A + (offA11 + kkN), nxtA + dA1 + 512);
            asm volatile("s_waitcnt vmcnt(4)" ::: "memory"); }   // A-lo,B-lo(t+1) done
    __builtin_amdgcn_s_barrier();
    __builtin_amdgcn_sched_barrier(0);
    __builtin_amdgcn_s_setprio(1);
    #pragma unroll
    for(int m=0;m<4;m++)
      #pragma unroll
      for(int n=0;n<2;n++){
        acc[4+m][2+n] = __builtin_amdgcn_mfma_f32_16x16x32_bf16(af[m][0], bgB[n][0], acc[4+m][2+n], 0,0,0);
        acc[4+m][2+n] = __builtin_amdgcn_mfma_f32_16x16x32_bf16(af[m][1], bgB[n][1], acc[4+m][2+n], 0,0,0);
      }
    __builtin_amdgcn_s_setprio(0);
    __builtin_amdgcn_s_barrier();
  }
  #undef DSR

  // epilogue
  #pragma unroll
  for(int mi=0;mi<8;mi++){
    const int rbase = tileRow + wr*128 + mi*16 + kq*4;
    #pragma unroll
    for(int n=0;n<4;n++){
      const int col = tileCol + wc*64 + n*16 + l15;
      #pragma unroll
      for(int rr=0; rr<4; rr++){
        const int rrow = rbase + rr;
        if(rrow >= M) continue;
        float v = acc[mi][n][rr];
        if(MODE==0){
          int part = col/DIM, cc = col - part*DIM;
          int head = cc>>6, d = cc&63;
          int bb = rrow/NTOK, nn = rrow - bb*NTOK;
          size_t bh = (size_t)bb*NHEAD + head;
          if(part==0){ v = (v + b0[cc])*ATTN_SCALE; o0[(bh*NTOK + nn)*HDIM + d] = f2bf(v); }
          else if(part==1){ o1[(bh*NTOK + nn)*HDIM + d] = f2bf(v); }
          else { v += b1[cc]; o2[(bh*HDIM + d)*VST + nn] = f2bf(v); }
        } else if(MODE==1){
          outf[(size_t)rrow*DIM + col] = v + b0[col] + resid[(size_t)rrow*DIM + col];
        } else if(MODE==2){
          o0[(size_t)rrow*MLP + col] = f2bf(gelu_f(v + b0[col]));
        } else {
          outf[(size_t)rrow*DIM + col] = v + b0[col] + resid[(size_t)rrow*DIM + col];
        }
      }
    }
  }
}

// ---- flash attention, no-max softmax (scores bounded; exp(s-SOFF) safe) ----
__global__ __launch_bounds__(256) void fattn_kernel(
    const u16* __restrict__ q, const u16* __restrict__ k, const u16* __restrict__ vt,
    const u16* __restrict__ rpb, u16* __restrict__ out)
{
  int bid = blockIdx.x;
  int qt = bid / 384;
  int rem = bid - qt*384;
  int h = rem >> 5, b = rem & 31;
  int bh = b*NHEAD + h;
  int r0 = qt*64;

  __shared__ __align__(16) u16 Ks[64][72];
  __shared__ __align__(16) u16 Vs[64][72];
  __shared__ __align__(16) u16 Rs[64][72];
  __shared__ __align__(16) u16 Pw[4][16][72];

  int tx = threadIdx.x, wave = tx>>6, lane = tx&63;
  int lcol = lane & 15;
  int quad = lane >> 4;
  int rw0 = r0 + wave*16;

  bf16x8 aq0 = {0,0,0,0,0,0,0,0}, aq1 = {0,0,0,0,0,0,0,0};
  {
    int qrow = rw0 + lcol;
    if(qrow < NTOK){
      const u16* qp = q + ((size_t)bh*NTOK + qrow)*HDIM + quad*8;
      aq0 = *(const bf16x8*)(qp);
      aq1 = *(const bf16x8*)(qp + 32);
    }
  }

  f32x4 o[4];
  #pragma unroll
  for(int j=0;j<4;j++){ f32x4 z={0.f,0.f,0.f,0.f}; o[j]=z; }
  float lpart[4] = {0.f,0.f,0.f,0.f};   // per-lane partial softmax mass

  int sr = tx>>3, sc = (tx&7)*8;

  const u16* kbase = k  + (size_t)bh*NTOK*HDIM;
  const u16* vbase = vt + (size_t)bh*HDIM*VST;
  const u16* rbase = rpb + ((size_t)h*NTOK + r0)*RST;

  for(int kt=0; kt<10; kt++){
    int key0 = kt*TK;
    *(bf16x8*)(&Ks[sr][sc])    = *(const bf16x8*)(kbase + (size_t)(key0+sr)*HDIM + sc);
    *(bf16x8*)(&Ks[32+sr][sc]) = *(const bf16x8*)(kbase + (size_t)(key0+32+sr)*HDIM + sc);
    *(bf16x8*)(&Vs[sr][sc])    = *(const bf16x8*)(vbase + (size_t)sr*VST + key0 + sc);
    *(bf16x8*)(&Vs[32+sr][sc]) = *(const bf16x8*)(vbase + (size_t)(32+sr)*VST + key0 + sc);
    *(bf16x8*)(&Rs[sr][sc])    = *(const bf16x8*)(rbase + (size_t)sr*RST + key0 + sc);
    *(bf16x8*)(&Rs[32+sr][sc]) = *(const bf16x8*)(rbase + (size_t)(32+sr)*RST + key0 + sc);
    __syncthreads();

    f32x4 s[4];
    #pragma unroll
    for(int c=0;c<4;c++){
      f32x4 z = {0.f,0.f,0.f,0.f};
      bf16x8 kb0 = *(const bf16x8*)(&Ks[16*c+lcol][quad*8]);
      bf16x8 kb1 = *(const bf16x8*)(&Ks[16*c+lcol][32+quad*8]);
      z = __builtin_amdgcn_mfma_f32_16x16x32_bf16(aq0, kb0, z, 0,0,0);
      z = __builtin_amdgcn_mfma_f32_16x16x32_bf16(aq1, kb1, z, 0,0,0);
      s[c] = z;
    }

    #pragma unroll
    for(int rr=0; rr<4; rr++){
      int qloc = wave*16 + quad*4 + rr;
      #pragma unroll
      for(int c=0;c<4;c++){
        int key = key0 + 16*c + lcol;
        float sv = (key < NTOK) ? s[c][rr] + bf2f(Rs[qloc][16*c+lcol]) : -1e30f;
        float pe = __expf(sv - SOFF);
        lpart[rr] += pe;
        Pw[wave][quad*4+rr][16*c+lcol] = f2bf(pe);
      }
    }
    bf16x8 ap0 = *(const bf16x8*)(&Pw[wave][lcol][quad*8]);
    bf16x8 ap1 = *(const bf16x8*)(&Pw[wave][lcol][32+quad*8]);
    #pragma unroll
    for(int j=0;j<4;j++){
      bf16x8 vb0 = *(const bf16x8*)(&Vs[16*j+lcol][quad*8]);
      bf16x8 vb1 = *(const bf16x8*)(&Vs[16*j+lcol][32+quad*8]);
      o[j] = __builtin_amdgcn_mfma_f32_16x16x32_bf16(ap0, vb0, o[j], 0,0,0);
      o[j] = __builtin_amdgcn_mfma_f32_16x16x32_bf16(ap1, vb1, o[j], 0,0,0);
    }
    __syncthreads();
  }

  // reduce softmax mass across the 16 lanes of each quad, then normalize
  #pragma unroll
  for(int rr=0;rr<4;rr++){
    float ts = lpart[rr];
    ts += __shfl_xor(ts, 1);
    ts += __shfl_xor(ts, 2);
    ts += __shfl_xor(ts, 4);
    ts += __shfl_xor(ts, 8);
    lpart[rr] = ts;
  }
  #pragma unroll
  for(int rr=0;rr<4;rr++){
    int n = rw0 + quad*4 + rr;
    if(n >= NTOK) continue;
    float inv = 1.0f / lpart[rr];
    u16* op = out + ((size_t)b*NTOK + n)*DIM + h*HDIM;
    #pragma unroll
    for(int j=0;j<4;j++)
      op[16*j + lcol] = f2bf(o[j][rr]*inv);
  }
}

extern "C" void kernel_launch(void* const* d_in, const int* in_sizes, int n_in,
                              void* d_out, int out_size, void* d_ws, size_t ws_size,
                              hipStream_t stream)
{
  const float* x      = (const float*)d_in[0];
  const float* n1g    = (const float*)d_in[1];
  const float* n1b    = (const float*)d_in[2];
  const float* qkvw   = (const float*)d_in[3];
  const float* qbias  = (const float*)d_in[4];
  const float* vbias  = (const float*)d_in[5];
  const float* rpbt   = (const float*)d_in[6];
  const float* projw  = (const float*)d_in[7];
  const float* projb  = (const float*)d_in[8];
  const float* n2g    = (const float*)d_in[9];
  const float* n2b    = (const float*)d_in[10];
  const float* fc1w   = (const float*)d_in[11];
  const float* fc1b   = (const float*)d_in[12];
  const float* fc2w   = (const float*)d_in[13];
  const float* fc2b   = (const float*)d_in[14];
  const int*   relidx = (const int*)d_in[15];

  char* ws = (char*)d_ws;
  const size_t WQ_OFF  = 0;
  const size_t WP_OFF  = 3538944;
  const size_t W1_OFF  = 4718592;
  const size_t W2_OFF  = 9437184;
  const size_t RPB_OFF = 14155776;
  const size_t H_OFF   = 30136576;
  const size_t Q_OFF   = H_OFF + 28360704;
  const size_t K_OFF   = Q_OFF + 28360704;
  const size_t V_OFF   = K_OFF + 28360704;
  const size_t ATT_OFF = V_OFF + 28704896;
  const size_t X1_OFF  = ATT_OFF + 28360704;
  const size_t M_OFF   = H_OFF;
  const size_t H2_OFF  = ATT_OFF;

  u16* wq   = (u16*)(ws + WQ_OFF);
  u16* wp   = (u16*)(ws + WP_OFF);
  u16* w1   = (u16*)(ws + W1_OFF);
  u16* w2   = (u16*)(ws + W2_OFF);
  u16* rpbb = (u16*)(ws + RPB_OFF);
  u16* hb   = (u16*)(ws + H_OFF);
  u16* qbuf = (u16*)(ws + Q_OFF);
  u16* kbuf = (u16*)(ws + K_OFF);
  u16* vbuf = (u16*)(ws + V_OFF);
  u16* attb = (u16*)(ws + ATT_OFF);
  float* x1 = (float*)(ws + X1_OFF);
  u16* mbuf = (u16*)(ws + M_OFF);
  u16* h2   = (u16*)(ws + H2_OFF);
  float* outp = (float*)d_out;

  const int ncvt = 2304*768 + 768*768 + 3072*768 + 3072*768;
  cvt4_kernel<<<(ncvt+255)/256, 256, 0, stream>>>(qkvw, 2304*768, projw, 768*768,
                                                  fc1w, 3072*768, fc2w, 3072*768,
                                                  wq, wp, w1, w2);
  rpb_kernel<<<(NHEAD*NTOK*NTOK+255)/256, 256, 0, stream>>>(relidx, rpbt, rpbb);

  ln_kernel<<<ROWS, 256, 0, stream>>>(x, n1g, n1b, hb);
  gemm_kernel<0,9><<<NRT2*9, 512, 0, stream>>>(hb, wq, ROWS, DIM, qbias, vbias,
                                               nullptr, nullptr, qbuf, kbuf, vbuf);
  fattn_kernel<<<10*384, 256, 0, stream>>>(qbuf, kbuf, vbuf, rpbb, attb);
  gemm_kernel<1,3><<<NRT2*3, 512, 0, stream>>>(attb, wp, ROWS, DIM, projb, nullptr,
                                               x, x1, nullptr, nullptr, nullptr);
  ln_kernel<<<ROWS, 256, 0, stream>>>(x1, n2g, n2b, h2);
  gemm_kernel<2,12><<<NRT2*12, 512, 0, stream>>>(h2, w1, ROWS, DIM, fc1b, nullptr,
                                                 nullptr, nullptr, mbuf, nullptr, nullptr);
  gemm_kernel<3,3><<<NRT2*3, 512, 0, stream>>>(mbuf, w2, ROWS, MLP, fc2b, nullptr,
                                               x1, outp, nullptr, nullptr, nullptr);
}

// Round 9
// 764.201 us; speedup vs baseline: 1.1621x; 1.1621x over previous
//
#include <hip/hip_runtime.h>
#include <hip/hip_bf16.h>
#include <math.h>

#define BATCH 32
#define NTOK 577
#define DIM 768
#define NHEAD 12
#define HDIM 64
#define MLP 3072
#define ROWS (BATCH*NTOK)
#define ATTN_SCALE 0.125f
#define LN_EPS 1e-6f
#define VST 584
#define RST 584
#define TK 64
#define NRT 145   // row tiles of 128 over 18464 rows
#define SOFF 20.0f

typedef unsigned short u16;
typedef unsigned int u32;
typedef __attribute__((ext_vector_type(8))) short bf16x8;
typedef __attribute__((ext_vector_type(4))) float f32x4;
typedef const __attribute__((address_space(3))) u16* lds_cp;

__device__ inline u16 f2bf(float f){
  u32 u = __float_as_uint(f);
  u32 r = (u + 0x7fffu + ((u>>16)&1u)) >> 16;
  return (u16)r;
}
__device__ inline float bf2f(u16 v){
  u32 u = ((u32)v)<<16; return __uint_as_float(u);
}

__device__ __forceinline__ void gload16(const u16* g, u16* l){
  __builtin_amdgcn_global_load_lds((const __attribute__((address_space(1))) void*)g,
                                   (__attribute__((address_space(3))) void*)l, 16, 0, 0);
}

// exact-erf GELU via A&S 7.1.26 rational approx (|err| < 1.5e-7)
__device__ inline float gelu_f(float v){
  float xa = fabsf(v)*0.70710678118654752f;
  float t = 1.0f/(1.0f + 0.3275911f*xa);
  float p = (((1.061405429f*t - 1.453152027f)*t + 1.421413741f)*t - 0.284496736f)*t + 0.254829592f;
  float erfv = 1.0f - p*t*__expf(-xa*xa);
  erfv = (v < 0.f) ? -erfv : erfv;
  return 0.5f*v*(1.0f + erfv);
}

// ---- fused weight conversion f32 -> bf16 ----
__global__ void cvt4_kernel(const float* __restrict__ s0, int n0,
                            const float* __restrict__ s1, int n1,
                            const float* __restrict__ s2, int n2,
                            const float* __restrict__ s3, int n3,
                            u16* __restrict__ d0, u16* __restrict__ d1,
                            u16* __restrict__ d2, u16* __restrict__ d3){
  int i = blockIdx.x*256 + threadIdx.x;
  if(i < n0){ d0[i] = f2bf(s0[i]); return; }
  i -= n0;
  if(i < n1){ d1[i] = f2bf(s1[i]); return; }
  i -= n1;
  if(i < n2){ d2[i] = f2bf(s2[i]); return; }
  i -= n2;
  if(i < n3){ d3[i] = f2bf(s3[i]); }
}

// ---- rpb precompute (bf16, padded row stride 584) ----
__global__ void rpb_kernel(const int* __restrict__ rel, const float* __restrict__ table, u16* __restrict__ bias){
  int i = blockIdx.x*256 + threadIdx.x;
  const int nm = NTOK*NTOK;
  if(i >= NHEAD*nm) return;
  int h = i / nm;
  int r = i - h*nm;
  int n = r / NTOK, m = r - n*NTOK;
  bias[((size_t)h*NTOK + n)*RST + m] = f2bf(table[rel[r]*NHEAD + h]);
}

// ---- LayerNorm ----
__global__ __launch_bounds__(256) void ln_kernel(const float* __restrict__ in, const float* __restrict__ g,
                                                 const float* __restrict__ b, u16* __restrict__ out){
  int row = blockIdx.x;
  const float* p = in + (size_t)row*DIM;
  int t = threadIdx.x;
  float v0 = p[t], v1 = p[t+256], v2 = p[t+512];
  float s = v0+v1+v2;
  #pragma unroll
  for(int off=32; off; off>>=1) s += __shfl_xor(s, off);
  __shared__ float red[8];
  int wv = t>>6;
  if((t&63)==0) red[wv] = s;
  __syncthreads();
  float mean = (red[0]+red[1]+red[2]+red[3]) * (1.0f/768.0f);
  float d0=v0-mean, d1=v1-mean, d2=v2-mean;
  float q = d0*d0 + d1*d1 + d2*d2;
  #pragma unroll
  for(int off=32; off; off>>=1) q += __shfl_xor(q, off);
  if((t&63)==0) red[4+wv] = q;
  __syncthreads();
  float var = (red[4]+red[5]+red[6]+red[7]) * (1.0f/768.0f);
  float inv = rsqrtf(var + LN_EPS);
  u16* po = out + (size_t)row*DIM;
  po[t]     = f2bf(d0*inv*g[t]     + b[t]);
  po[t+256] = f2bf(d1*inv*g[t+256] + b[t+256]);
  po[t+512] = f2bf(d2*inv*g[t+512] + b[t+512]);
}

// ---- 128x256 bf16 MFMA GEMM, BK=32, ring-3 depth-2, counted vmcnt,
// inline-asm ds_read (r7's verified pipeline at 2x N-tile economics).
// 8 waves (2M x 4N), per-wave 64x64 output. vs r7 (128x128): blocks halve,
// staged bytes -25% (A restaged over half the col tiles), barriers and
// staging instrs per output halve, same 8 ds_read + 16 MFMA per wave-tile.
// LDS: ring of 3 x (8KB A + 16KB B) = 72 KB -> 2 blocks/CU (16 waves).
// Line scheme (r5/r7-verified, 0 bank conflicts): per 8KB sub-buffer,
// line l (128B) holds rows {l, l+64} as 8 16B slots; phys slot =
// logical ^ (l&7); staged linear glds dest + inverse-permuted GLOBAL src.
// B [256][32] = two 8KB sub-buffers (rows 0-127 / 128-255).
// Staging per thread per tile: 1 A + 2 B gloads. Counted vmcnt: at tile u
// issue STAGE(u+2) -> vmcnt(6) retires exactly tile u's 3 loads (u+1,u+2
// stay in flight ACROSS the barrier) -> s_barrier -> asm ds_read (base +
// offset:2048j immediates, slot bases precomputed -> no per-tile addr VALU)
// -> lgkmcnt(0) + sched_barrier(0) (rule #18) -> 16 MFMA -> s_barrier.
// Tail 3 -> 0. NT = K/32 in {24,96}, divisible by 3. ----
template<int MODE, int NC>
__global__ __launch_bounds__(512) void gemm_kernel(
    const u16* __restrict__ A, const u16* __restrict__ Bt,
    int M, int K,
    const float* __restrict__ b0, const float* __restrict__ b1,
    const float* __restrict__ resid, float* __restrict__ outf,
    u16* __restrict__ o0, u16* __restrict__ o1, u16* __restrict__ o2)
{
  __shared__ __align__(16) u16 As[3][4096];   // 8KB per slot
  __shared__ __align__(16) u16 Bs[3][8192];   // 16KB per slot

  int id = blockIdx.x;
  int xcd = id & 7, sblk = id >> 3;
  int rg = sblk / NC, c = sblk - rg*NC;
  int r = xcd + 8*rg;
  if(r >= NRT) return;
  const int rowTile = r*128, colTile = c*256;

  const int tx = threadIdx.x;
  const int wave = tx>>6, lane = tx&63;
  const int wr = (wave>>2)*64;          // M half (0/64)
  const int wc = (wave&3)*64;           // N quarter (0/64/128/192)
  const int lrow = lane&15, kq = lane>>4, l7 = lane&7;

  // ---- staging source permutation (inverse of the read swizzle) ----
  const int sl  = (lane&7) ^ (lane>>3);            // logical slot this lane feeds
  const int hr  = sl>>2;                           // row-half within line
  const int c8  = (sl&3)*8;                        // col offset (elems)
  // A: 8 waves x 1 gload cover [128][32]; wave owns lines 8w..8w+7
  const int rowA = 8*wave + (lane>>3) + 64*hr;
  const u32 offA = (u32)min(rowTile + rowA, M-1)*(u32)K + c8;
  const int dstA = wave*512;                       // elems, wave-uniform
  // B: waves 0-3 -> rows 0-127 (sub 0), waves 4-7 -> rows 128-255 (sub 1);
  // within group: r5's 2-gload pattern
  const int grp = wave>>2, w4 = wave&3;
  const int rowB = grp*128 + 16*w4 + (lane>>3) + 64*hr;
  const u32 offB0 = (u32)(colTile + rowB)*(u32)K + c8;
  const u32 offB1 = offB0 + 8u*(u32)K;
  const int dstB0 = grp*4096 + (2*w4)*512, dstB1 = dstB0 + 512;

  // ---- frag read base offsets (elems), loop-invariant ----
  const int eA0 = lrow*64 + (((kq + (wr>>4)) ^ l7)*8);
  const int eB0 = (wc>>7)*4096 + lrow*64 + (((kq + ((wc>>4)&4)) ^ l7)*8);
  lds_cp pA0 = (lds_cp)&As[0][eA0], pA1 = (lds_cp)&As[1][eA0], pA2 = (lds_cp)&As[2][eA0];
  lds_cp pB0 = (lds_cp)&Bs[0][eB0], pB1 = (lds_cp)&Bs[1][eB0], pB2 = (lds_cp)&Bs[2][eB0];

  f32x4 acc[4][4];
  #pragma unroll
  for(int i=0;i<4;i++)
    #pragma unroll
    for(int j=0;j<4;j++){ f32x4 z = {0.f,0.f,0.f,0.f}; acc[i][j]=z; }

  #define STAGEH(S, KOFF) { \
    gload16(A  + (offA  + (KOFF)), &As[S][dstA]); \
    gload16(Bt + (offB0 + (KOFF)), &Bs[S][dstB0]); \
    gload16(Bt + (offB1 + (KOFF)), &Bs[S][dstB1]); \
  }

  #define COMPUTE(PA, PB) { \
    bf16x8 af_[4], bf_[4]; \
    asm volatile("ds_read_b128 %0, %1"             : "=v"(af_[0]) : "v"(PA)); \
    asm volatile("ds_read_b128 %0, %1 offset:2048" : "=v"(af_[1]) : "v"(PA)); \
    asm volatile("ds_read_b128 %0, %1 offset:4096" : "=v"(af_[2]) : "v"(PA)); \
    asm volatile("ds_read_b128 %0, %1 offset:6144" : "=v"(af_[3]) : "v"(PA)); \
    asm volatile("ds_read_b128 %0, %1"             : "=v"(bf_[0]) : "v"(PB)); \
    asm volatile("ds_read_b128 %0, %1 offset:2048" : "=v"(bf_[1]) : "v"(PB)); \
    asm volatile("ds_read_b128 %0, %1 offset:4096" : "=v"(bf_[2]) : "v"(PB)); \
    asm volatile("ds_read_b128 %0, %1 offset:6144" : "=v"(bf_[3]) : "v"(PB)); \
    asm volatile("s_waitcnt lgkmcnt(0)" ::: "memory"); \
    __builtin_amdgcn_sched_barrier(0); \
    _Pragma("unroll") \
    for(int i_=0;i_<4;i_++) \
      _Pragma("unroll") \
      for(int j_=0;j_<4;j_++) \
        acc[i_][j_] = __builtin_amdgcn_mfma_f32_16x16x32_bf16(af_[i_], bf_[j_], acc[i_][j_], 0,0,0); \
  }

  // one pipeline stage: tile U in ring slot S, prefetch U+2 into (S+2)%3
  #define PHASE(S, PAx, PBx, U) { \
    if((U)+2 < NT){ \
      STAGEH(((S)+2)%3, (u32)((U)+2)<<5); \
      asm volatile("s_waitcnt vmcnt(6)" ::: "memory"); \
    } else if((U)+1 < NT){ \
      asm volatile("s_waitcnt vmcnt(3)" ::: "memory"); \
    } else { \
      asm volatile("s_waitcnt vmcnt(0)" ::: "memory"); \
    } \
    __builtin_amdgcn_s_barrier(); \
    COMPUTE(PAx, PBx); \
    __builtin_amdgcn_s_barrier(); \
  }

  const int NT = K >> 5;   // 24 or 96 -- both divisible by 3 (required)
  STAGEH(0, 0u);
  STAGEH(1, 1u<<5);
  for(int t=0; t<NT; t+=3){
    PHASE(0, pA0, pB0, t);
    PHASE(1, pA1, pB1, t+1);
    PHASE(2, pA2, pB2, t+2);
  }
  #undef PHASE
  #undef STAGEH
  #undef COMPUTE

  #pragma unroll
  for(int i=0;i<4;i++){
    int rbase = rowTile + wr + i*16 + kq*4;
    #pragma unroll
    for(int j=0;j<4;j++){
      int col = colTile + wc + j*16 + lrow;
      #pragma unroll
      for(int rr=0; rr<4; rr++){
        int rrow = rbase + rr;
        if(rrow >= M) continue;
        float v = acc[i][j][rr];
        if(MODE==0){
          int part = col/DIM, cc = col - part*DIM;
          int head = cc>>6, d = cc&63;
          int bb = rrow/NTOK, n = rrow - bb*NTOK;
          size_t bh = (size_t)bb*NHEAD + head;
          if(part==0){ v = (v + b0[cc])*ATTN_SCALE; o0[(bh*NTOK + n)*HDIM + d] = f2bf(v); }
          else if(part==1){ o1[(bh*NTOK + n)*HDIM + d] = f2bf(v); }
          else { v += b1[cc]; o2[(bh*HDIM + d)*VST + n] = f2bf(v); }
        } else if(MODE==1){
          outf[(size_t)rrow*DIM + col] = v + b0[col] + resid[(size_t)rrow*DIM + col];
        } else if(MODE==2){
          o0[(size_t)rrow*MLP + col] = f2bf(gelu_f(v + b0[col]));
        } else {
          outf[(size_t)rrow*DIM + col] = v + b0[col] + resid[(size_t)rrow*DIM + col];
        }
      }
    }
  }
}

// ---- flash attention, no-max softmax (scores bounded; exp(s-SOFF) safe) ----
__global__ __launch_bounds__(256) void fattn_kernel(
    const u16* __restrict__ q, const u16* __restrict__ k, const u16* __restrict__ vt,
    const u16* __restrict__ rpb, u16* __restrict__ out)
{
  int bid = blockIdx.x;
  int qt = bid / 384;
  int rem = bid - qt*384;
  int h = rem >> 5, b = rem & 31;
  int bh = b*NHEAD + h;
  int r0 = qt*64;

  __shared__ __align__(16) u16 Ks[64][72];
  __shared__ __align__(16) u16 Vs[64][72];
  __shared__ __align__(16) u16 Rs[64][72];
  __shared__ __align__(16) u16 Pw[4][16][72];

  int tx = threadIdx.x, wave = tx>>6, lane = tx&63;
  int lcol = lane & 15;
  int quad = lane >> 4;
  int rw0 = r0 + wave*16;

  bf16x8 aq0 = {0,0,0,0,0,0,0,0}, aq1 = {0,0,0,0,0,0,0,0};
  {
    int qrow = rw0 + lcol;
    if(qrow < NTOK){
      const u16* qp = q + ((size_t)bh*NTOK + qrow)*HDIM + quad*8;
      aq0 = *(const bf16x8*)(qp);
      aq1 = *(const bf16x8*)(qp + 32);
    }
  }

  f32x4 o[4];
  #pragma unroll
  for(int j=0;j<4;j++){ f32x4 z={0.f,0.f,0.f,0.f}; o[j]=z; }
  float lpart[4] = {0.f,0.f,0.f,0.f};   // per-lane partial softmax mass

  int sr = tx>>3, sc = (tx&7)*8;

  const u16* kbase = k  + (size_t)bh*NTOK*HDIM;
  const u16* vbase = vt + (size_t)bh*HDIM*VST;
  const u16* rbase = rpb + ((size_t)h*NTOK + r0)*RST;

  for(int kt=0; kt<10; kt++){
    int key0 = kt*TK;
    *(bf16x8*)(&Ks[sr][sc])    = *(const bf16x8*)(kbase + (size_t)(key0+sr)*HDIM + sc);
    *(bf16x8*)(&Ks[32+sr][sc]) = *(const bf16x8*)(kbase + (size_t)(key0+32+sr)*HDIM + sc);
    *(bf16x8*)(&Vs[sr][sc])    = *(const bf16x8*)(vbase + (size_t)sr*VST + key0 + sc);
    *(bf16x8*)(&Vs[32+sr][sc]) = *(const bf16x8*)(vbase + (size_t)(32+sr)*VST + key0 + sc);
    *(bf16x8*)(&Rs[sr][sc])    = *(const bf16x8*)(rbase + (size_t)sr*RST + key0 + sc);
    *(bf16x8*)(&Rs[32+sr][sc]) = *(const bf16x8*)(rbase + (size_t)(32+sr)*RST + key0 + sc);
    __syncthreads();

    f32x4 s[4];
    #pragma unroll
    for(int c=0;c<4;c++){
      f32x4 z = {0.f,0.f,0.f,0.f};
      bf16x8 kb0 = *(const bf16x8*)(&Ks[16*c+lcol][quad*8]);
      bf16x8 kb1 = *(const bf16x8*)(&Ks[16*c+lcol][32+quad*8]);
      z = __builtin_amdgcn_mfma_f32_16x16x32_bf16(aq0, kb0, z, 0,0,0);
      z = __builtin_amdgcn_mfma_f32_16x16x32_bf16(aq1, kb1, z, 0,0,0);
      s[c] = z;
    }

    #pragma unroll
    for(int rr=0; rr<4; rr++){
      int qloc = wave*16 + quad*4 + rr;
      #pragma unroll
      for(int c=0;c<4;c++){
        int key = key0 + 16*c + lcol;
        float sv = (key < NTOK) ? s[c][rr] + bf2f(Rs[qloc][16*c+lcol]) : -1e30f;
        float pe = __expf(sv - SOFF);
        lpart[rr] += pe;
        Pw[wave][quad*4+rr][16*c+lcol] = f2bf(pe);
      }
    }
    bf16x8 ap0 = *(const bf16x8*)(&Pw[wave][lcol][quad*8]);
    bf16x8 ap1 = *(const bf16x8*)(&Pw[wave][lcol][32+quad*8]);
    #pragma unroll
    for(int j=0;j<4;j++){
      bf16x8 vb0 = *(const bf16x8*)(&Vs[16*j+lcol][quad*8]);
      bf16x8 vb1 = *(const bf16x8*)(&Vs[16*j+lcol][32+quad*8]);
      o[j] = __builtin_amdgcn_mfma_f32_16x16x32_bf16(ap0, vb0, o[j], 0,0,0);
      o[j] = __builtin_amdgcn_mfma_f32_16x16x32_bf16(ap1, vb1, o[j], 0,0,0);
    }
    __syncthreads();
  }

  // reduce softmax mass across the 16 lanes of each quad, then normalize
  #pragma unroll
  for(int rr=0;rr<4;rr++){
    float ts = lpart[rr];
    ts += __shfl_xor(ts, 1);
    ts += __shfl_xor(ts, 2);
    ts += __shfl_xor(ts, 4);
    ts += __shfl_xor(ts, 8);
    lpart[rr] = ts;
  }
  #pragma unroll
  for(int rr=0;rr<4;rr++){
    int n = rw0 + quad*4 + rr;
    if(n >= NTOK) continue;
    float inv = 1.0f / lpart[rr];
    u16* op = out + ((size_t)b*NTOK + n)*DIM + h*HDIM;
    #pragma unroll
    for(int j=0;j<4;j++)
      op[16*j + lcol] = f2bf(o[j][rr]*inv);
  }
}

extern "C" void kernel_launch(void* const* d_in, const int* in_sizes, int n_in,
                              void* d_out, int out_size, void* d_ws, size_t ws_size,
                              hipStream_t stream)
{
  const float* x      = (const float*)d_in[0];
  const float* n1g    = (const float*)d_in[1];
  const float* n1b    = (const float*)d_in[2];
  const float* qkvw   = (const float*)d_in[3];
  const float* qbias  = (const float*)d_in[4];
  const float* vbias  = (const float*)d_in[5];
  const float* rpbt   = (const float*)d_in[6];
  const float* projw  = (const float*)d_in[7];
  const float* projb  = (const float*)d_in[8];
  const float* n2g    = (const float*)d_in[9];
  const float* n2b    = (const float*)d_in[10];
  const float* fc1w   = (const float*)d_in[11];
  const float* fc1b   = (const float*)d_in[12];
  const float* fc2w   = (const float*)d_in[13];
  const float* fc2b   = (const float*)d_in[14];
  const int*   relidx = (const int*)d_in[15];

  char* ws = (char*)d_ws;
  const size_t WQ_OFF  = 0;
  const size_t WP_OFF  = 3538944;
  const size_t W1_OFF  = 4718592;
  const size_t W2_OFF  = 9437184;
  const size_t RPB_OFF = 14155776;
  const size_t H_OFF   = 30136576;
  const size_t Q_OFF   = H_OFF + 28360704;
  const size_t K_OFF   = Q_OFF + 28360704;
  const size_t V_OFF   = K_OFF + 28360704;
  const size_t ATT_OFF = V_OFF + 28704896;
  const size_t X1_OFF  = ATT_OFF + 28360704;
  const size_t M_OFF   = H_OFF;
  const size_t H2_OFF  = ATT_OFF;

  u16* wq   = (u16*)(ws + WQ_OFF);
  u16* wp   = (u16*)(ws + WP_OFF);
  u16* w1   = (u16*)(ws + W1_OFF);
  u16* w2   = (u16*)(ws + W2_OFF);
  u16* rpbb = (u16*)(ws + RPB_OFF);
  u16* hb   = (u16*)(ws + H_OFF);
  u16* qbuf = (u16*)(ws + Q_OFF);
  u16* kbuf = (u16*)(ws + K_OFF);
  u16* vbuf = (u16*)(ws + V_OFF);
  u16* attb = (u16*)(ws + ATT_OFF);
  float* x1 = (float*)(ws + X1_OFF);
  u16* mbuf = (u16*)(ws + M_OFF);
  u16* h2   = (u16*)(ws + H2_OFF);
  float* outp = (float*)d_out;

  const int ncvt = 2304*768 + 768*768 + 3072*768 + 3072*768;
  cvt4_kernel<<<(ncvt+255)/256, 256, 0, stream>>>(qkvw, 2304*768, projw, 768*768,
                                                  fc1w, 3072*768, fc2w, 3072*768,
                                                  wq, wp, w1, w2);
  rpb_kernel<<<(NHEAD*NTOK*NTOK+255)/256, 256, 0, stream>>>(relidx, rpbt, rpbb);

  const int GRP = 8 * ((NRT + 7)/8);   // 152

  ln_kernel<<<ROWS, 256, 0, stream>>>(x, n1g, n1b, hb);
  gemm_kernel<0,9><<<GRP*9, 512, 0, stream>>>(hb, wq, ROWS, DIM, qbias, vbias,
                                              nullptr, nullptr, qbuf, kbuf, vbuf);
  fattn_kernel<<<10*384, 256, 0, stream>>>(qbuf, kbuf, vbuf, rpbb, attb);
  gemm_kernel<1,3><<<GRP*3, 512, 0, stream>>>(attb, wp, ROWS, DIM, projb, nullptr,
                                              x, x1, nullptr, nullptr, nullptr);
  ln_kernel<<<ROWS, 256, 0, stream>>>(x1, n2g, n2b, h2);
  gemm_kernel<2,12><<<GRP*12, 512, 0, stream>>>(h2, w1, ROWS, DIM, fc1b, nullptr,
                                                nullptr, nullptr, mbuf, nullptr, nullptr);
  gemm_kernel<3,3><<<GRP*3, 512, 0, stream>>>(mbuf, w2, ROWS, MLP, fc2b, nullptr,
                                              x1, outp, nullptr, nullptr, nullptr);
}